// Round 1
// 1799.336 us; speedup vs baseline: 1.4792x; 1.4792x over previous
//
#include <hip/hip_runtime.h>
#include <hip/hip_bf16.h>
#include <hip/hip_fp16.h>
#include <cstdint>
#include <cstddef>

// B=128 T=96 D=256 H=256 C=8 M=64, COMB=1280
// gates = zc + h @ Uh^T + t @ G^T   (gate interleave n=4j+g)
//   Uh[n][256] = W_h[j] + W_xi[j]@Wfc      (k_fold)
//   G [n][512] = sum_d W_gd[n][d]*mem[cm][d]  (k_foldG)
//   zc[t*128+b][n] = bias2[n] + [z|zp] @ Uz^T  (fp16, k_zc)
// NEW: x_i eliminated from the loop.
//   scores[r][cm] = SzM[r][cm] + h @ Q^T[cm]
//     Q[cm][j]  = sum_{d in c} mem[cm][d]*lw2[d]*Wfc[d][j]   (k_foldQ, static)
//     SzM[r][cm]= sum_{d in c} mem[cm][d]*(lw0 z+lw1 zp)[r][d] + qb[cm] (k_szm GEMM)
//   out = hSeq[1..96] @ Wfc^T + bfc  (k_out post-pass GEMM)
// k_main: 128 blocks = 8 groups(16 rows) x 16 slices(64 gate cols),
// 2 group barriers/step (h, t), split arrive/wait to hide h-part MFMA.

#define PLANE 24576   // 96*256
#define GRP 16        // slices per group

using bf16_t = __hip_bfloat16;
typedef __bf16 bf16x8 __attribute__((ext_vector_type(8)));
typedef float  f32x4  __attribute__((ext_vector_type(4)));

__device__ __forceinline__ float  b2f(bf16_t v){ return __bfloat162float(v); }
__device__ __forceinline__ bf16_t f2b(float v){ return __float2bfloat16(v); }
__device__ __forceinline__ float ldF(const void* p, size_t i, int f32){
  return f32 ? ((const float*)p)[i] : b2f(((const bf16_t*)p)[i]);
}
__device__ __forceinline__ bf16x8 ld_frag(const void* p){
  union { uint4 u; bf16x8 v; } c;
  c.u = *(const uint4*)p;
  return c.v;
}
__device__ __forceinline__ f32x4 mfma_bf16(bf16x8 a, bf16x8 b, f32x4 c){
  return __builtin_amdgcn_mfma_f32_16x16x32_bf16(a, b, c, 0, 0, 0);
}

// split group barrier: arrive (release) / wait (acquire), monotonic counter
__device__ __forceinline__ void g_arrive(int* ctr){
  __syncthreads();                 // drains all threads' prior stores (vmcnt 0)
  if (threadIdx.x == 0){
    __threadfence();
    atomicAdd(ctr, 1);
  }
}
__device__ __forceinline__ void g_wait(int* ctr, int target){
  if (threadIdx.x == 0){
    while (atomicAdd(ctr, 0) < target) __builtin_amdgcn_s_sleep(1);
    __threadfence();
  }
  __syncthreads();
}

// ---------------- dtype detection ----------------
__global__ __launch_bounds__(64) void k_detect(
    const uint32_t* __restrict__ xu, const uint32_t* __restrict__ clu,
    int* __restrict__ flags)
{
  __shared__ int cnt[2];
  int t = threadIdx.x;
  if (t < 2) cnt[t] = 0;
  __syncthreads();
  uint32_t v = xu[2*PLANE + t];
  if (v == 0u || v == 0x3F800000u) atomicAdd(&cnt[0], 1);
  if (clu[2*t + 1] == 0u) atomicAdd(&cnt[1], 1);
  __syncthreads();
  if (t == 0){
    flags[0] = (cnt[0] >= 48) ? 1 : 0;
    flags[1] = (cnt[1] >= 60) ? 1 : 0;
  }
}

__global__ __launch_bounds__(256) void k_zero(int* __restrict__ bar){
  bar[threadIdx.x] = 0;
}

// ---------------- canonicalize small tensors ----------------
__global__ __launch_bounds__(256) void k_canon(
    const void* __restrict__ Wfc, const void* __restrict__ Xmean,
    const void* __restrict__ bfc, const void* __restrict__ localw,
    const void* __restrict__ globalw, const void* __restrict__ gzw,
    const void* __restrict__ gzb, const void* __restrict__ gzpw,
    const void* __restrict__ gzpb, const int* __restrict__ flags,
    bf16_t* __restrict__ WfcC, bf16_t* __restrict__ XmC,
    bf16_t* __restrict__ bfcC, bf16_t* __restrict__ lwC,
    bf16_t* __restrict__ gwC, float* __restrict__ gzC)
{
  const int f32 = flags[0];
  int i = blockIdx.x*256 + threadIdx.x;
  if (i < 65536) WfcC[i] = f2b(ldF(Wfc, i, f32));
  if (i < 24576) XmC[i]  = f2b(ldF(Xmean, i, f32));
  if (i < 256)   bfcC[i] = f2b(ldF(bfc, i, f32));
  if (i < 768)   lwC[i]  = f2b(ldF(localw, i, f32));
  if (i < 8)     gwC[i]  = f2b(ldF(globalw, i, f32));
  if (i < 256){
    gzC[i]       = ldF(gzw,  i, f32);
    gzC[256 + i] = ldF(gzb,  i, f32);
    gzC[512 + i] = ldF(gzpw, i, f32);
    gzC[768 + i] = ldF(gzpb, i, f32);
  }
}

// ---------------- weight folding: U(h-part folded), Uz, bias2 ----------------
__global__ __launch_bounds__(256) void k_fold(
    const void* __restrict__ Wi, const void* __restrict__ Wf,
    const void* __restrict__ Wo, const void* __restrict__ Wc,
    const void* __restrict__ bi, const void* __restrict__ bfg,
    const void* __restrict__ bo, const void* __restrict__ bcg,
    const void* __restrict__ Wfc, const void* __restrict__ bfc,
    const int* __restrict__ flags,
    bf16_t* __restrict__ U, bf16_t* __restrict__ Uz, float* __restrict__ bias2)
{
  const int f32 = flags[0];
  int n = blockIdx.x; int g = n & 3; int j = n >> 2;
  const void* Wg = (g==0)?Wi:(g==1)?Wf:(g==2)?Wo:Wc;
  const void* bg = (g==0)?bi:(g==1)?bfg:(g==2)?bo:bcg;
  const size_t wb = (size_t)j*1280;
  int k = threadIdx.x;
  float acc = 0.f;
  for (int d=0; d<256; ++d)
    acc += ldF(Wg, wb+512+d, f32) * ldF(Wfc, (size_t)d*256+k, f32);
  U[(size_t)n*512 + k]        = f2b(acc + ldF(Wg, wb+1024+k, f32));
  U[(size_t)n*512 + 256 + k]  = f2b(ldF(Wg, wb+768+k, f32));   // unused
  Uz[(size_t)n*512 + k]       = f2b(ldF(Wg, wb+k, f32));
  Uz[(size_t)n*512 + 256 + k] = f2b(ldF(Wg, wb+256+k, f32));
  __shared__ float red[256];
  red[k] = ldF(Wg, wb+512+k, f32) * ldF(bfc, k, f32);
  __syncthreads();
  for (int s=128; s>0; s>>=1){ if (k<s) red[k]+=red[k+s]; __syncthreads(); }
  if (k==0) bias2[n] = red[0] + ldF(bg, j, f32);
}

// ---------------- G[n][cm] = sum_d W_gd[n][d] * mem[cm][d] ----------------
__global__ __launch_bounds__(256) void k_foldG(
    const void* __restrict__ Wi, const void* __restrict__ Wf,
    const void* __restrict__ Wo, const void* __restrict__ Wc,
    const void* __restrict__ memory, const int* __restrict__ flags,
    bf16_t* __restrict__ G)
{
  const int f32 = flags[0];
  __shared__ float wrow[4][256];
  int j = blockIdx.x; int tid = threadIdx.x;
  const void* Wg[4] = {Wi,Wf,Wo,Wc};
  for (int g=0; g<4; ++g)
    wrow[g][tid] = ldF(Wg[g], (size_t)j*1280 + 768 + tid, f32);
  __syncthreads();
  for (int half=0; half<2; ++half){
    int cm = half*256 + tid;
    float a0=0,a1=0,a2=0,a3=0;
    for (int d=0; d<256; ++d){
      float mv = ldF(memory, (size_t)cm*256 + d, f32);
      a0 += wrow[0][d]*mv; a1 += wrow[1][d]*mv;
      a2 += wrow[2][d]*mv; a3 += wrow[3][d]*mv;
    }
    G[(size_t)(4*j+0)*512 + cm] = f2b(a0);
    G[(size_t)(4*j+1)*512 + cm] = f2b(a1);
    G[(size_t)(4*j+2)*512 + cm] = f2b(a2);
    G[(size_t)(4*j+3)*512 + cm] = f2b(a3);
  }
}

// -------- Q[cm][j] = sum_{d in c} mem[cm][d]*lw2[d]*Wfc[d][j];
//          Mem2[cm][d] = masked mem (for SzM GEMM); qb[cm] = sum ml2*bfc ------
__global__ __launch_bounds__(256) void k_foldQ(
    const int* __restrict__ clusters, const void* __restrict__ memory,
    const bf16_t* __restrict__ lwC, const bf16_t* __restrict__ WfcC,
    const bf16_t* __restrict__ bfcC, const int* __restrict__ flags,
    bf16_t* __restrict__ Mem2, bf16_t* __restrict__ Qbf, float* __restrict__ qb)
{
  const int f32 = flags[0], i64 = flags[1];
  const int cm = blockIdx.x; const int c = cm >> 6;
  const int tid = threadIdx.x;
  __shared__ float ml2[256];
  __shared__ float red[256];
  int cv = i64 ? clusters[2*tid] : clusters[tid];
  float mv = (cv == c+1) ? ldF(memory, (size_t)cm*256 + tid, f32) : 0.f;
  Mem2[(size_t)cm*256 + tid] = f2b(mv);
  float m2 = mv * b2f(lwC[512 + tid]);
  ml2[tid] = m2;
  red[tid] = m2 * b2f(bfcC[tid]);
  __syncthreads();
  float acc = 0.f;
  for (int d=0; d<256; ++d)
    acc += ml2[d] * b2f(WfcC[(size_t)d*256 + tid]);
  Qbf[(size_t)cm*256 + tid] = f2b(acc);
  for (int s=128; s>0; s>>=1){ if (tid<s) red[tid]+=red[tid+s]; __syncthreads(); }
  if (tid==0) qb[cm] = red[0];
}

// ---------------- z / zp -> Zcat + Zl = lw0*z+lw1*zp, t-major rows ----------
__global__ __launch_bounds__(256) void k_zzp(
    const void* __restrict__ x, const bf16_t* __restrict__ XmC,
    const float* __restrict__ gzC, const bf16_t* __restrict__ lwC,
    const int* __restrict__ flags,
    bf16_t* __restrict__ Zcat, bf16_t* __restrict__ Zl)
{
  const int f32 = flags[0];
  int r = blockIdx.x;             // r = t*128 + b
  int t = r >> 7, b = r & 127, d = threadIdx.x;
  size_t base = (size_t)b*6*PLANE + (size_t)t*256 + d;
  float xt = ldF(x, base          , f32);
  float xl = ldF(x, base +   PLANE, f32);
  float mk = ldF(x, base + 2*PLANE, f32);
  float de = ldF(x, base + 3*PLANE, f32);
  float xlb= ldF(x, base + 4*PLANE, f32);
  float deb= ldF(x, base + 5*PLANE, f32);
  float mean = b2f(XmC[t*256+d]);
  float dz  = expf(-fmaxf(0.f, de *gzC[d]     + gzC[256+d]));
  float dzp = expf(-fmaxf(0.f, deb*gzC[512+d] + gzC[768+d]));
  float z  = mk*xt + (1.f-mk)*(dz *xl  + (1.f-dz )*mean);
  float zp = mk*xt + (1.f-mk)*(dzp*xlb + (1.f-dzp)*mean);
  Zcat[(size_t)r*512 + d]       = f2b(z);
  Zcat[(size_t)r*512 + 256 + d] = f2b(zp);
  Zl[(size_t)r*256 + d] = f2b(b2f(lwC[d])*z + b2f(lwC[256+d])*zp);
}

// ---------------- zc GEMM: zc[m][n] = bias2[n] + Zcat[m] @ Uz^T (fp16) ------
__global__ __launch_bounds__(256) void k_zc(
    const bf16_t* __restrict__ Zcat, const bf16_t* __restrict__ Uz,
    const float* __restrict__ bias2, __half* __restrict__ zc)
{
  const int tid = threadIdx.x;
  const int w = tid>>6, l = tid&63, q=l>>4, cl=l&15;
  const int mq = w&1, nq = w>>1;
  const int m0 = blockIdx.x*128, n0 = blockIdx.y*128;
  f32x4 acc[4][4];
#pragma unroll
  for (int a=0;a<4;++a)
#pragma unroll
    for (int b2=0;b2<4;++b2) acc[a][b2] = (f32x4){0.f,0.f,0.f,0.f};
  for (int ks=0; ks<16; ++ks){
    bf16x8 av[4], bv[4];
#pragma unroll
    for (int mi=0;mi<4;++mi)
      av[mi] = ld_frag(&Zcat[(size_t)(m0+mq*64+mi*16+cl)*512 + ks*32 + q*8]);
#pragma unroll
    for (int ni=0;ni<4;++ni)
      bv[ni] = ld_frag(&Uz[(size_t)(n0+nq*64+ni*16+cl)*512 + ks*32 + q*8]);
#pragma unroll
    for (int mi=0;mi<4;++mi)
#pragma unroll
      for (int ni=0;ni<4;++ni)
        acc[mi][ni] = mfma_bf16(av[mi], bv[ni], acc[mi][ni]);
  }
#pragma unroll
  for (int mi=0;mi<4;++mi)
#pragma unroll
    for (int ni=0;ni<4;++ni)
#pragma unroll
      for (int rr=0;rr<4;++rr){
        int m = m0 + mq*64 + mi*16 + q*4 + rr;
        int n = n0 + nq*64 + ni*16 + cl;
        zc[(size_t)m*1024 + n] = __float2half(acc[mi][ni][rr] + bias2[n]);
      }
}

// ---------------- SzM GEMM: SzM[m][cm] = qb[cm] + Zl[m] @ Mem2^T (fp16) -----
__global__ __launch_bounds__(256) void k_szm(
    const bf16_t* __restrict__ Zl, const bf16_t* __restrict__ Mem2,
    const float* __restrict__ qb, __half* __restrict__ SzM)
{
  const int tid = threadIdx.x;
  const int w = tid>>6, l = tid&63, q=l>>4, cl=l&15;
  const int mq = w&1, nq = w>>1;
  const int m0 = blockIdx.x*128, n0 = blockIdx.y*128;
  f32x4 acc[4][4];
#pragma unroll
  for (int a=0;a<4;++a)
#pragma unroll
    for (int b2=0;b2<4;++b2) acc[a][b2] = (f32x4){0.f,0.f,0.f,0.f};
  for (int ks=0; ks<8; ++ks){
    bf16x8 av[4], bv[4];
#pragma unroll
    for (int mi=0;mi<4;++mi)
      av[mi] = ld_frag(&Zl[(size_t)(m0+mq*64+mi*16+cl)*256 + ks*32 + q*8]);
#pragma unroll
    for (int ni=0;ni<4;++ni)
      bv[ni] = ld_frag(&Mem2[(size_t)(n0+nq*64+ni*16+cl)*256 + ks*32 + q*8]);
#pragma unroll
    for (int mi=0;mi<4;++mi)
#pragma unroll
      for (int ni=0;ni<4;++ni)
        acc[mi][ni] = mfma_bf16(av[mi], bv[ni], acc[mi][ni]);
  }
#pragma unroll
  for (int mi=0;mi<4;++mi)
#pragma unroll
    for (int ni=0;ni<4;++ni)
#pragma unroll
      for (int rr=0;rr<4;++rr){
        int m = m0 + mq*64 + mi*16 + q*4 + rr;
        int n = n0 + nq*64 + ni*16 + cl;
        SzM[(size_t)m*512 + n] = __float2half(acc[mi][ni][rr] + qb[n]);
      }
}

// ---------------- output GEMM: out[b][t][:] = hSeq[t+1][b] @ Wfc^T + bfc ----
__global__ __launch_bounds__(256) void k_out(
    const bf16_t* __restrict__ hSeq, const bf16_t* __restrict__ WfcC,
    const bf16_t* __restrict__ bfcC, const int* __restrict__ flags,
    void* __restrict__ outv)
{
  const int f32 = flags[0];
  const int tid = threadIdx.x;
  const int w = tid>>6, l = tid&63, q=l>>4, cl=l&15;
  const int mq = w&1, nq = w>>1;
  const int m0 = blockIdx.x*128, n0 = blockIdx.y*128;
  f32x4 acc[4][4];
#pragma unroll
  for (int a=0;a<4;++a)
#pragma unroll
    for (int b2=0;b2<4;++b2) acc[a][b2] = (f32x4){0.f,0.f,0.f,0.f};
  for (int ks=0; ks<8; ++ks){
    bf16x8 av[4], bv[4];
#pragma unroll
    for (int mi=0;mi<4;++mi)
      av[mi] = ld_frag(&hSeq[(size_t)(128 + m0+mq*64+mi*16+cl)*256 + ks*32 + q*8]);
#pragma unroll
    for (int ni=0;ni<4;++ni)
      bv[ni] = ld_frag(&WfcC[(size_t)(n0+nq*64+ni*16+cl)*256 + ks*32 + q*8]);
#pragma unroll
    for (int mi=0;mi<4;++mi)
#pragma unroll
      for (int ni=0;ni<4;++ni)
        acc[mi][ni] = mfma_bf16(av[mi], bv[ni], acc[mi][ni]);
  }
#pragma unroll
  for (int mi=0;mi<4;++mi)
#pragma unroll
    for (int ni=0;ni<4;++ni)
#pragma unroll
      for (int rr=0;rr<4;++rr){
        int m = m0 + mq*64 + mi*16 + q*4 + rr;    // m = t*128 + b
        int n = n0 + nq*64 + ni*16 + cl;
        float v = acc[mi][ni][rr] + b2f(bfcC[n]);
        int b = m & 127, tt = m >> 7;
        size_t ob = ((size_t)b*96 + tt)*256 + n;
        if (f32) ((float*)outv)[ob] = v; else ((bf16_t*)outv)[ob] = f2b(v);
      }
}

// ---------------- k_main: 128 blocks (8 groups x 16 slices) x 256 thr -------
// per step: [wait h] -> scores+softmax+t-write (s<8) -> arrive B ->
//           h-part MFMA (hidden under B wait) -> [wait t] -> t@G -> LSTM -> h
__global__ __launch_bounds__(256) void k_main(
    const bf16_t* __restrict__ gwC,
    const bf16_t* __restrict__ U, const bf16_t* __restrict__ G,
    const bf16_t* __restrict__ Qbf,
    const __half* __restrict__ zc, const __half* __restrict__ SzM,
    bf16_t* __restrict__ hSeq, bf16_t* __restrict__ tSeq,
    int* __restrict__ bar)
{
  __shared__ bf16_t Us[64][264];    // Uh slice rows n0..n0+63
  __shared__ bf16_t Gs[64][520];    // G  slice
  __shared__ bf16_t Qs[64][264];    // Q rows for own cluster (s<8)
  __shared__ bf16_t hS[16][264];
  __shared__ bf16_t tS[16][520];
  __shared__ float redmx[4][16];
  __shared__ float redsm[4][16];

  const int tid = threadIdx.x;
  const int W = tid>>6, l = tid&63, q = l>>4, cl = l&15;
  const int g = blockIdx.x & 7, s = blockIdx.x >> 3;  // group g -> XCD g
  const int r0 = g*16;
  const int n0 = s*64;
  int* barp = bar + g*32;           // [0]=barA(h), [16]=barB(t), own cachelines

  // one-time staging (LDS-resident weights, all 96 steps)
  for (int i=tid; i<64*32; i+=256){ int r=i>>5, c8=(i&31)*8;
    *(uint4*)(&Us[r][c8]) = *(const uint4*)(U + (size_t)(n0+r)*512 + c8); }
  for (int i=tid; i<64*64; i+=256){ int r=i>>6, c8=(i&63)*8;
    *(uint4*)(&Gs[r][c8]) = *(const uint4*)(G + (size_t)(n0+r)*512 + c8); }
  if (s<8)
    for (int i=tid; i<64*32; i+=256){ int r=i>>5, c8=(i&31)*8;
      *(uint4*)(&Qs[r][c8]) = *(const uint4*)(Qbf + (size_t)(s*64+r)*256 + c8); }
  for (int i=tid; i<16*264; i+=256) hS[i/264][i%264] = f2b(0.f);
  const float gw_c = (s<8)? b2f(gwC[s]) : 0.f;
  float creg[4] = {0.f,0.f,0.f,0.f};
  __syncthreads();

  for (int t=0; t<96; ++t){
    // prefetch zc / SzM for this step (independent of h -> overlaps barA wait)
    f32x4 acc;
#pragma unroll
    for (int rr=0; rr<4; ++rr)
      acc[rr] = __half2float(zc[((size_t)(t*128)+r0+q*4+rr)*1024 + n0 + W*16 + cl]);
    f32x4 sa = {0.f,0.f,0.f,0.f};
    if (s<8){
#pragma unroll
      for (int rr=0; rr<4; ++rr)
        sa[rr] = __half2float(SzM[((size_t)(t*128)+r0+q*4+rr)*512 + s*64 + W*16 + cl]);
    }
    if (t>0){
      g_wait(barp+0, GRP*t);        // h(t-1) visible
      const bf16_t* hsrc = hSeq + (size_t)t*128*256;
      for (int i=tid; i<16*32; i+=256){ int r=i>>5, c8=(i&31)*8;
        *(uint4*)(&hS[r][c8]) = *(const uint4*)(hsrc + (size_t)(r0+r)*256 + c8); }
      __syncthreads();
    }
    // cluster blocks: scores = SzM + h @ Q^T, softmax over 64 slots, write t
    if (s<8){
#pragma unroll
      for (int ks=0; ks<8; ++ks){
        bf16x8 a = ld_frag(&hS[cl][ks*32 + q*8]);
        bf16x8 b = ld_frag(&Qs[W*16+cl][ks*32 + q*8]);
        sa = mfma_bf16(a, b, sa);
      }
      // per-row max over 64 cols = (16 lanes cl) x (4 waves)
#pragma unroll
      for (int rr=0; rr<4; ++rr){
        float m = sa[rr];
        m = fmaxf(m, __shfl_xor(m,1));
        m = fmaxf(m, __shfl_xor(m,2));
        m = fmaxf(m, __shfl_xor(m,4));
        m = fmaxf(m, __shfl_xor(m,8));
        if (cl==0) redmx[W][q*4+rr] = m;
      }
      __syncthreads();
      float e4[4];
#pragma unroll
      for (int rr=0; rr<4; ++rr){
        int row = q*4+rr;
        float mx = fmaxf(fmaxf(redmx[0][row],redmx[1][row]),
                         fmaxf(redmx[2][row],redmx[3][row]));
        float e = expf(sa[rr]-mx);
        e4[rr] = e;
        float ss = e;
        ss += __shfl_xor(ss,1); ss += __shfl_xor(ss,2);
        ss += __shfl_xor(ss,4); ss += __shfl_xor(ss,8);
        if (cl==0) redsm[W][row] = ss;
      }
      __syncthreads();
      bf16_t* tdst = tSeq + (size_t)t*128*512;
#pragma unroll
      for (int rr=0; rr<4; ++rr){
        int row = q*4+rr;
        float sm = redsm[0][row]+redsm[1][row]+redsm[2][row]+redsm[3][row];
        tdst[(size_t)(r0+row)*512 + s*64 + W*16 + cl] = f2b(e4[rr]*gw_c/sm);
      }
    }
    g_arrive(barp+16);              // t written (or nothing to write)
    // gate h-part overlapped with barB wait: nothing before barB needs it
#pragma unroll
    for (int ks=0; ks<8; ++ks){
      bf16x8 a = ld_frag(&hS[cl][ks*32 + q*8]);
      bf16x8 b = ld_frag(&Us[W*16+cl][ks*32 + q*8]);
      acc = mfma_bf16(a, b, acc);
    }
    g_wait(barp+16, GRP*(t+1));     // t slices visible
    {
      const bf16_t* tsrc = tSeq + (size_t)t*128*512;
      for (int i=tid; i<16*64; i+=256){ int r=i>>6, c8=(i&63)*8;
        *(uint4*)(&tS[r][c8]) = *(const uint4*)(tsrc + (size_t)(r0+r)*512 + c8); }
      __syncthreads();
    }
    // gate gd-part: acc += t @ G^T
#pragma unroll
    for (int ks=0; ks<16; ++ks){
      bf16x8 a = ld_frag(&tS[cl][ks*32 + q*8]);
      bf16x8 b = ld_frag(&Gs[W*16+cl][ks*32 + q*8]);
      acc = mfma_bf16(a, b, acc);
    }
    // LSTM update: lanes quad = (i,f,o,c) of one j
    const int base = l & ~3;
    bf16_t* hdst = hSeq + (size_t)(t+1)*128*256;
#pragma unroll
    for (int rr=0; rr<4; ++rr){
      float p = acc[rr];
      float pi = __shfl(p, base+0);
      float pf = __shfl(p, base+1);
      float po = __shfl(p, base+2);
      float pc = __shfl(p, base+3);
      float iv = 1.f/(1.f+expf(-pi));
      float fv = 1.f/(1.f+expf(-pf));
      float ov = 1.f/(1.f+expf(-po));
      float cv = tanhf(pc);
      float cn = fv*creg[rr] + iv*cv;
      creg[rr] = cn;
      float hv = ov * tanhf(cn);
      if ((l&3)==0)
        hdst[(size_t)(r0+q*4+rr)*256 + s*16 + W*4 + (cl>>2)] = f2b(hv);
    }
    g_arrive(barp+0);               // h(t) written
  }
}

extern "C" void kernel_launch(void* const* d_in, const int* in_sizes, int n_in,
                              void* d_out, int out_size, void* d_ws, size_t ws_size,
                              hipStream_t stream)
{
  const void* x       = d_in[0];
  const void* Xmean   = d_in[1];
  const int*  clusters= (const int*)d_in[2];
  const void* Wi  = d_in[3];
  const void* bi  = d_in[4];
  const void* Wf  = d_in[5];
  const void* bfp = d_in[6];
  const void* Wo  = d_in[7];
  const void* bo  = d_in[8];
  const void* Wc  = d_in[9];
  const void* bcp = d_in[10];
  const void* Wfc = d_in[11];
  const void* bfc = d_in[12];
  const void* gzw = d_in[13];
  const void* gzb = d_in[14];
  const void* gzpw= d_in[15];
  const void* gzpb= d_in[16];
  const void* memory = d_in[17];
  const void* localw = d_in[18];
  const void* globalw= d_in[19];
  (void)in_sizes; (void)n_in; (void)out_size; (void)ws_size;

  char* ws = (char*)d_ws;
  size_t off = 0;
  auto take = [&](size_t bytes)->char*{
    char* p = ws + off; off = (off + bytes + 255) & ~(size_t)255; return p; };
  int*    flags  = (int*)   take(16);
  int*    bar    = (int*)   take(256*4);
  bf16_t* U      = (bf16_t*)take((size_t)1024*512*2);     // 1 MB
  bf16_t* Uz     = (bf16_t*)take((size_t)1024*512*2);     // 1 MB
  bf16_t* G      = (bf16_t*)take((size_t)1024*512*2);     // 1 MB
  bf16_t* WfcC   = (bf16_t*)take((size_t)65536*2);
  bf16_t* XmC    = (bf16_t*)take((size_t)24576*2);
  bf16_t* bfcC   = (bf16_t*)take(256*2);
  bf16_t* lwC    = (bf16_t*)take(768*2);
  bf16_t* gwC    = (bf16_t*)take(8*2);
  float*  gzC    = (float*) take(1024*4);
  float*  bias2  = (float*) take(1024*4);
  bf16_t* Mem2   = (bf16_t*)take((size_t)512*256*2);      // 256 KB
  bf16_t* Qbf    = (bf16_t*)take((size_t)512*256*2);      // 256 KB
  float*  qb     = (float*) take(512*4);
  __half* zc     = (__half*)take((size_t)12288*1024*2);   // 25.2 MB
  __half* SzM    = (__half*)take((size_t)12288*512*2);    // 12.6 MB
  // aliased regions (strictly sequential producers/consumers in-stream):
  //   bigA: Zcat (k_zzp->k_zc) then tSeq (k_main)        -- both 12.58 MB
  //   bigB: Zl   (k_zzp->k_szm) then hSeq (k_main->k_out)
  char* bigA = take((size_t)12288*512*2);
  char* bigB = take((size_t)97*128*256*2);
  bf16_t* Zcat = (bf16_t*)bigA;
  bf16_t* tSeq = (bf16_t*)bigA;
  bf16_t* Zl   = (bf16_t*)bigB;
  bf16_t* hSeq = (bf16_t*)bigB;

  k_detect<<<1,    64, 0,stream>>>((const uint32_t*)x, (const uint32_t*)clusters, flags);
  k_zero  <<<1,    256,0,stream>>>(bar);
  k_canon <<<256,  256,0,stream>>>(Wfc, Xmean, bfc, localw, globalw,
                                   gzw, gzb, gzpw, gzpb, flags,
                                   WfcC, XmC, bfcC, lwC, gwC, gzC);
  k_fold  <<<1024, 256,0,stream>>>(Wi,Wf,Wo,Wc, bi,bfp,bo,bcp, Wfc,bfc, flags,
                                   U, Uz, bias2);
  k_foldG <<<256,  256,0,stream>>>(Wi,Wf,Wo,Wc, memory, flags, G);
  k_foldQ <<<512,  256,0,stream>>>(clusters, memory, lwC, WfcC, bfcC, flags,
                                   Mem2, Qbf, qb);
  k_zzp   <<<12288,256,0,stream>>>(x, XmC, gzC, lwC, flags, Zcat, Zl);
  k_zc    <<<dim3(96,8),256,0,stream>>>(Zcat, Uz, bias2, zc);
  k_szm   <<<dim3(96,4),256,0,stream>>>(Zl, Mem2, qb, SzM);
  k_main  <<<128,  256,0,stream>>>(gwC, U, G, Qbf, zc, SzM, hSeq, tSeq, bar);
  k_out   <<<dim3(96,2),256,0,stream>>>(hSeq, WfcC, bfcC, flags, d_out);
}

// Round 3
// 1046.755 us; speedup vs baseline: 2.5426x; 1.7190x over previous
//
#include <hip/hip_runtime.h>
#include <hip/hip_bf16.h>
#include <hip/hip_fp16.h>
#include <cstdint>
#include <cstddef>

// B=128 T=96 D=256 H=256 C=8 M=64, COMB=1280
// gates = zc + h @ Uh^T + t @ G^T   (gate interleave n=4j+g)
//   Uh[n][256] = W_h[j] + W_xi[j]@Wfc      (k_fold)
//   G [n][512] = sum_d W_gd[n][d]*mem[cm][d]  (k_foldG)
//   zc[t*128+b][n] = bias2[n] + [z|zp] @ Uz^T  (fp16, k_zc)
// x_i eliminated from the loop:
//   scores[r][cm] = SzM[r][cm] + h @ Q^T[cm]  (k_foldQ static, k_szm GEMM)
//   out = hSeq[1..96] @ Wfc^T + bfc  (k_out post-pass GEMM)
// k_main: 128 blocks = 8 groups(16 rows) x 16 slices(64 gate cols),
// 2 group barriers/step. Fence-free exchange: h/t tiles published with
// sc0|sc1 write-through stores (visible at LLC), consumed with sc0|sc1 loads,
// flags via relaxed atomicAdd. No buffer_wbl2/buffer_inv on the hot path.

#define PLANE 24576   // 96*256
#define GRP 16        // slices per group

using bf16_t = __hip_bfloat16;
typedef __bf16 bf16x8 __attribute__((ext_vector_type(8)));
typedef float  f32x4  __attribute__((ext_vector_type(4)));
typedef unsigned int u32x4 __attribute__((ext_vector_type(4)));

__device__ __forceinline__ float  b2f(bf16_t v){ return __bfloat162float(v); }
__device__ __forceinline__ bf16_t f2b(float v){ return __float2bfloat16(v); }
__device__ __forceinline__ float ldF(const void* p, size_t i, int f32){
  return f32 ? ((const float*)p)[i] : b2f(((const bf16_t*)p)[i]);
}
__device__ __forceinline__ bf16x8 ld_frag(const void* p){
  union { uint4 u; bf16x8 v; } c;
  c.u = *(const uint4*)p;
  return c.v;
}
__device__ __forceinline__ f32x4 mfma_bf16(bf16x8 a, bf16x8 b, f32x4 c){
  return __builtin_amdgcn_mfma_f32_16x16x32_bf16(a, b, c, 0, 0, 0);
}

// ---- coherent (LLC-level) access helpers: no L2 writeback/invalidate needed
__device__ __forceinline__ u32x4 ld_cg(const void* p){
  u32x4 r;
  asm volatile("global_load_dwordx4 %0, %1, off sc0 sc1"
               : "=v"(r) : "v"(p) : "memory");
  return r;
}
__device__ __forceinline__ void st_cg(void* p, u32x4 v){
  asm volatile("global_store_dwordx4 %0, %1, off sc0 sc1"
               :: "v"(p), "v"(v) : "memory");
}
__device__ __forceinline__ int ld_flag(const int* p){
  int r;
  asm volatile("global_load_dword %0, %1, off sc0 sc1\n\ts_waitcnt vmcnt(0)"
               : "=v"(r) : "v"(p) : "memory");
  return r;
}
__device__ __forceinline__ void vm_wait0(){
  asm volatile("s_waitcnt vmcnt(0)" ::: "memory");
  __builtin_amdgcn_sched_barrier(0);
}

// ---------------- dtype detection ----------------
__global__ __launch_bounds__(64) void k_detect(
    const uint32_t* __restrict__ xu, const uint32_t* __restrict__ clu,
    int* __restrict__ flags)
{
  __shared__ int cnt[2];
  int t = threadIdx.x;
  if (t < 2) cnt[t] = 0;
  __syncthreads();
  uint32_t v = xu[2*PLANE + t];
  if (v == 0u || v == 0x3F800000u) atomicAdd(&cnt[0], 1);
  if (clu[2*t + 1] == 0u) atomicAdd(&cnt[1], 1);
  __syncthreads();
  if (t == 0){
    flags[0] = (cnt[0] >= 48) ? 1 : 0;
    flags[1] = (cnt[1] >= 60) ? 1 : 0;
  }
}

__global__ __launch_bounds__(256) void k_zero(int* __restrict__ bar){
  bar[threadIdx.x] = 0;
}

// ---------------- canonicalize small tensors ----------------
__global__ __launch_bounds__(256) void k_canon(
    const void* __restrict__ Wfc, const void* __restrict__ Xmean,
    const void* __restrict__ bfc, const void* __restrict__ localw,
    const void* __restrict__ globalw, const void* __restrict__ gzw,
    const void* __restrict__ gzb, const void* __restrict__ gzpw,
    const void* __restrict__ gzpb, const int* __restrict__ flags,
    bf16_t* __restrict__ WfcC, bf16_t* __restrict__ XmC,
    bf16_t* __restrict__ bfcC, bf16_t* __restrict__ lwC,
    bf16_t* __restrict__ gwC, float* __restrict__ gzC)
{
  const int f32 = flags[0];
  int i = blockIdx.x*256 + threadIdx.x;
  if (i < 65536) WfcC[i] = f2b(ldF(Wfc, i, f32));
  if (i < 24576) XmC[i]  = f2b(ldF(Xmean, i, f32));
  if (i < 256)   bfcC[i] = f2b(ldF(bfc, i, f32));
  if (i < 768)   lwC[i]  = f2b(ldF(localw, i, f32));
  if (i < 8)     gwC[i]  = f2b(ldF(globalw, i, f32));
  if (i < 256){
    gzC[i]       = ldF(gzw,  i, f32);
    gzC[256 + i] = ldF(gzb,  i, f32);
    gzC[512 + i] = ldF(gzpw, i, f32);
    gzC[768 + i] = ldF(gzpb, i, f32);
  }
}

// ---------------- weight folding: U(h-part folded), Uz, bias2 ----------------
__global__ __launch_bounds__(256) void k_fold(
    const void* __restrict__ Wi, const void* __restrict__ Wf,
    const void* __restrict__ Wo, const void* __restrict__ Wc,
    const void* __restrict__ bi, const void* __restrict__ bfg,
    const void* __restrict__ bo, const void* __restrict__ bcg,
    const void* __restrict__ Wfc, const void* __restrict__ bfc,
    const int* __restrict__ flags,
    bf16_t* __restrict__ U, bf16_t* __restrict__ Uz, float* __restrict__ bias2)
{
  const int f32 = flags[0];
  int n = blockIdx.x; int g = n & 3; int j = n >> 2;
  const void* Wg = (g==0)?Wi:(g==1)?Wf:(g==2)?Wo:Wc;
  const void* bg = (g==0)?bi:(g==1)?bfg:(g==2)?bo:bcg;
  const size_t wb = (size_t)j*1280;
  int k = threadIdx.x;
  float acc = 0.f;
  for (int d=0; d<256; ++d)
    acc += ldF(Wg, wb+512+d, f32) * ldF(Wfc, (size_t)d*256+k, f32);
  U[(size_t)n*512 + k]        = f2b(acc + ldF(Wg, wb+1024+k, f32));
  U[(size_t)n*512 + 256 + k]  = f2b(ldF(Wg, wb+768+k, f32));   // unused
  Uz[(size_t)n*512 + k]       = f2b(ldF(Wg, wb+k, f32));
  Uz[(size_t)n*512 + 256 + k] = f2b(ldF(Wg, wb+256+k, f32));
  __shared__ float red[256];
  red[k] = ldF(Wg, wb+512+k, f32) * ldF(bfc, k, f32);
  __syncthreads();
  for (int s=128; s>0; s>>=1){ if (k<s) red[k]+=red[k+s]; __syncthreads(); }
  if (k==0) bias2[n] = red[0] + ldF(bg, j, f32);
}

// ---------------- G[n][cm] = sum_d W_gd[n][d] * mem[cm][d] ----------------
__global__ __launch_bounds__(256) void k_foldG(
    const void* __restrict__ Wi, const void* __restrict__ Wf,
    const void* __restrict__ Wo, const void* __restrict__ Wc,
    const void* __restrict__ memory, const int* __restrict__ flags,
    bf16_t* __restrict__ G)
{
  const int f32 = flags[0];
  __shared__ float wrow[4][256];
  int j = blockIdx.x; int tid = threadIdx.x;
  const void* Wg[4] = {Wi,Wf,Wo,Wc};
  for (int g=0; g<4; ++g)
    wrow[g][tid] = ldF(Wg[g], (size_t)j*1280 + 768 + tid, f32);
  __syncthreads();
  for (int half=0; half<2; ++half){
    int cm = half*256 + tid;
    float a0=0,a1=0,a2=0,a3=0;
    for (int d=0; d<256; ++d){
      float mv = ldF(memory, (size_t)cm*256 + d, f32);
      a0 += wrow[0][d]*mv; a1 += wrow[1][d]*mv;
      a2 += wrow[2][d]*mv; a3 += wrow[3][d]*mv;
    }
    G[(size_t)(4*j+0)*512 + cm] = f2b(a0);
    G[(size_t)(4*j+1)*512 + cm] = f2b(a1);
    G[(size_t)(4*j+2)*512 + cm] = f2b(a2);
    G[(size_t)(4*j+3)*512 + cm] = f2b(a3);
  }
}

// -------- Q[cm][j] = sum_{d in c} mem[cm][d]*lw2[d]*Wfc[d][j];
//          Mem2[cm][d] = masked mem; qb[cm] = sum ml2*bfc ------
__global__ __launch_bounds__(256) void k_foldQ(
    const int* __restrict__ clusters, const void* __restrict__ memory,
    const bf16_t* __restrict__ lwC, const bf16_t* __restrict__ WfcC,
    const bf16_t* __restrict__ bfcC, const int* __restrict__ flags,
    bf16_t* __restrict__ Mem2, bf16_t* __restrict__ Qbf, float* __restrict__ qb)
{
  const int f32 = flags[0], i64 = flags[1];
  const int cm = blockIdx.x; const int c = cm >> 6;
  const int tid = threadIdx.x;
  __shared__ float ml2[256];
  __shared__ float red[256];
  int cv = i64 ? clusters[2*tid] : clusters[tid];
  float mv = (cv == c+1) ? ldF(memory, (size_t)cm*256 + tid, f32) : 0.f;
  Mem2[(size_t)cm*256 + tid] = f2b(mv);
  float m2 = mv * b2f(lwC[512 + tid]);
  ml2[tid] = m2;
  red[tid] = m2 * b2f(bfcC[tid]);
  __syncthreads();
  float acc = 0.f;
  for (int d=0; d<256; ++d)
    acc += ml2[d] * b2f(WfcC[(size_t)d*256 + tid]);
  Qbf[(size_t)cm*256 + tid] = f2b(acc);
  for (int s=128; s>0; s>>=1){ if (tid<s) red[tid]+=red[tid+s]; __syncthreads(); }
  if (tid==0) qb[cm] = red[0];
}

// ---------------- z / zp -> Zcat + Zl = lw0*z+lw1*zp, t-major rows ----------
__global__ __launch_bounds__(256) void k_zzp(
    const void* __restrict__ x, const bf16_t* __restrict__ XmC,
    const float* __restrict__ gzC, const bf16_t* __restrict__ lwC,
    const int* __restrict__ flags,
    bf16_t* __restrict__ Zcat, bf16_t* __restrict__ Zl)
{
  const int f32 = flags[0];
  int r = blockIdx.x;             // r = t*128 + b
  int t = r >> 7, b = r & 127, d = threadIdx.x;
  size_t base = (size_t)b*6*PLANE + (size_t)t*256 + d;
  float xt = ldF(x, base          , f32);
  float xl = ldF(x, base +   PLANE, f32);
  float mk = ldF(x, base + 2*PLANE, f32);
  float de = ldF(x, base + 3*PLANE, f32);
  float xlb= ldF(x, base + 4*PLANE, f32);
  float deb= ldF(x, base + 5*PLANE, f32);
  float mean = b2f(XmC[t*256+d]);
  float dz  = expf(-fmaxf(0.f, de *gzC[d]     + gzC[256+d]));
  float dzp = expf(-fmaxf(0.f, deb*gzC[512+d] + gzC[768+d]));
  float z  = mk*xt + (1.f-mk)*(dz *xl  + (1.f-dz )*mean);
  float zp = mk*xt + (1.f-mk)*(dzp*xlb + (1.f-dzp)*mean);
  Zcat[(size_t)r*512 + d]       = f2b(z);
  Zcat[(size_t)r*512 + 256 + d] = f2b(zp);
  Zl[(size_t)r*256 + d] = f2b(b2f(lwC[d])*z + b2f(lwC[256+d])*zp);
}

// ---------------- zc GEMM: zc[m][n] = bias2[n] + Zcat[m] @ Uz^T (fp16) ------
__global__ __launch_bounds__(256) void k_zc(
    const bf16_t* __restrict__ Zcat, const bf16_t* __restrict__ Uz,
    const float* __restrict__ bias2, __half* __restrict__ zc)
{
  const int tid = threadIdx.x;
  const int w = tid>>6, l = tid&63, q=l>>4, cl=l&15;
  const int mq = w&1, nq = w>>1;
  const int m0 = blockIdx.x*128, n0 = blockIdx.y*128;
  f32x4 acc[4][4];
#pragma unroll
  for (int a=0;a<4;++a)
#pragma unroll
    for (int b2=0;b2<4;++b2) acc[a][b2] = (f32x4){0.f,0.f,0.f,0.f};
  for (int ks=0; ks<16; ++ks){
    bf16x8 av[4], bv[4];
#pragma unroll
    for (int mi=0;mi<4;++mi)
      av[mi] = ld_frag(&Zcat[(size_t)(m0+mq*64+mi*16+cl)*512 + ks*32 + q*8]);
#pragma unroll
    for (int ni=0;ni<4;++ni)
      bv[ni] = ld_frag(&Uz[(size_t)(n0+nq*64+ni*16+cl)*512 + ks*32 + q*8]);
#pragma unroll
    for (int mi=0;mi<4;++mi)
#pragma unroll
      for (int ni=0;ni<4;++ni)
        acc[mi][ni] = mfma_bf16(av[mi], bv[ni], acc[mi][ni]);
  }
#pragma unroll
  for (int mi=0;mi<4;++mi)
#pragma unroll
    for (int ni=0;ni<4;++ni)
#pragma unroll
      for (int rr=0;rr<4;++rr){
        int m = m0 + mq*64 + mi*16 + q*4 + rr;
        int n = n0 + nq*64 + ni*16 + cl;
        zc[(size_t)m*1024 + n] = __float2half(acc[mi][ni][rr] + bias2[n]);
      }
}

// ---------------- SzM GEMM: SzM[m][cm] = qb[cm] + Zl[m] @ Mem2^T (fp16) -----
__global__ __launch_bounds__(256) void k_szm(
    const bf16_t* __restrict__ Zl, const bf16_t* __restrict__ Mem2,
    const float* __restrict__ qb, __half* __restrict__ SzM)
{
  const int tid = threadIdx.x;
  const int w = tid>>6, l = tid&63, q=l>>4, cl=l&15;
  const int mq = w&1, nq = w>>1;
  const int m0 = blockIdx.x*128, n0 = blockIdx.y*128;
  f32x4 acc[4][4];
#pragma unroll
  for (int a=0;a<4;++a)
#pragma unroll
    for (int b2=0;b2<4;++b2) acc[a][b2] = (f32x4){0.f,0.f,0.f,0.f};
  for (int ks=0; ks<8; ++ks){
    bf16x8 av[4], bv[4];
#pragma unroll
    for (int mi=0;mi<4;++mi)
      av[mi] = ld_frag(&Zl[(size_t)(m0+mq*64+mi*16+cl)*256 + ks*32 + q*8]);
#pragma unroll
    for (int ni=0;ni<4;++ni)
      bv[ni] = ld_frag(&Mem2[(size_t)(n0+nq*64+ni*16+cl)*256 + ks*32 + q*8]);
#pragma unroll
    for (int mi=0;mi<4;++mi)
#pragma unroll
      for (int ni=0;ni<4;++ni)
        acc[mi][ni] = mfma_bf16(av[mi], bv[ni], acc[mi][ni]);
  }
#pragma unroll
  for (int mi=0;mi<4;++mi)
#pragma unroll
    for (int ni=0;ni<4;++ni)
#pragma unroll
      for (int rr=0;rr<4;++rr){
        int m = m0 + mq*64 + mi*16 + q*4 + rr;
        int n = n0 + nq*64 + ni*16 + cl;
        SzM[(size_t)m*512 + n] = __float2half(acc[mi][ni][rr] + qb[n]);
      }
}

// ---------------- output GEMM: out[b][t][:] = hSeq[t+1][b] @ Wfc^T + bfc ----
__global__ __launch_bounds__(256) void k_out(
    const bf16_t* __restrict__ hSeq, const bf16_t* __restrict__ WfcC,
    const bf16_t* __restrict__ bfcC, const int* __restrict__ flags,
    void* __restrict__ outv)
{
  const int f32 = flags[0];
  const int tid = threadIdx.x;
  const int w = tid>>6, l = tid&63, q=l>>4, cl=l&15;
  const int mq = w&1, nq = w>>1;
  const int m0 = blockIdx.x*128, n0 = blockIdx.y*128;
  f32x4 acc[4][4];
#pragma unroll
  for (int a=0;a<4;++a)
#pragma unroll
    for (int b2=0;b2<4;++b2) acc[a][b2] = (f32x4){0.f,0.f,0.f,0.f};
  for (int ks=0; ks<8; ++ks){
    bf16x8 av[4], bv[4];
#pragma unroll
    for (int mi=0;mi<4;++mi)
      av[mi] = ld_frag(&hSeq[(size_t)(128 + m0+mq*64+mi*16+cl)*256 + ks*32 + q*8]);
#pragma unroll
    for (int ni=0;ni<4;++ni)
      bv[ni] = ld_frag(&WfcC[(size_t)(n0+nq*64+ni*16+cl)*256 + ks*32 + q*8]);
#pragma unroll
    for (int mi=0;mi<4;++mi)
#pragma unroll
      for (int ni=0;ni<4;++ni)
        acc[mi][ni] = mfma_bf16(av[mi], bv[ni], acc[mi][ni]);
  }
#pragma unroll
  for (int mi=0;mi<4;++mi)
#pragma unroll
    for (int ni=0;ni<4;++ni)
#pragma unroll
      for (int rr=0;rr<4;++rr){
        int m = m0 + mq*64 + mi*16 + q*4 + rr;    // m = t*128 + b
        int n = n0 + nq*64 + ni*16 + cl;
        float v = acc[mi][ni][rr] + b2f(bfcC[n]);
        int b = m & 127, tt = m >> 7;
        size_t ob = ((size_t)b*96 + tt)*256 + n;
        if (f32) ((float*)outv)[ob] = v; else ((bf16_t*)outv)[ob] = f2b(v);
      }
}

// ---------------- k_main: 128 blocks (8 groups x 16 slices) x 256 thr -------
// per step: [wait h] -> scores+softmax (s<8) -> publish t -> arrive B ->
//           h-part MFMA (hidden under B wait) -> [wait t] -> t@G -> LSTM ->
//           publish h -> arrive A.  All exchange via sc0|sc1 (LLC), no fences.
__global__ __launch_bounds__(256) void k_main(
    const bf16_t* __restrict__ gwC,
    const bf16_t* __restrict__ U, const bf16_t* __restrict__ G,
    const bf16_t* __restrict__ Qbf,
    const __half* __restrict__ zc, const __half* __restrict__ SzM,
    bf16_t* __restrict__ hSeq, bf16_t* __restrict__ tSeq,
    int* __restrict__ bar)
{
  __shared__ bf16_t Us[64][264];    // Uh slice rows n0..n0+63
  __shared__ bf16_t Gs[64][520];    // G  slice
  __shared__ bf16_t Qs[64][264];    // Q rows for own cluster (s<8)
  __shared__ bf16_t hS[16][264];
  __shared__ bf16_t tS[16][520];
  __shared__ bf16_t hO[16][16];     // staged h output tile (coalesced flush)
  __shared__ bf16_t tO[16][64];     // staged t output tile (s<8)
  __shared__ float redmx[4][16];
  __shared__ float redsm[4][16];

  const int tid = threadIdx.x;
  const int W = tid>>6, l = tid&63, q = l>>4, cl = l&15;
  const int g = blockIdx.x & 7, s = blockIdx.x >> 3;  // group g -> XCD g
  const int r0 = g*16;
  const int n0 = s*64;
  int* barp = bar + g*32;           // [0]=barA(h), [16]=barB(t)

  // one-time staging (LDS-resident weights, all 96 steps)
  for (int i=tid; i<64*32; i+=256){ int r=i>>5, c8=(i&31)*8;
    *(uint4*)(&Us[r][c8]) = *(const uint4*)(U + (size_t)(n0+r)*512 + c8); }
  for (int i=tid; i<64*64; i+=256){ int r=i>>6, c8=(i&63)*8;
    *(uint4*)(&Gs[r][c8]) = *(const uint4*)(G + (size_t)(n0+r)*512 + c8); }
  if (s<8)
    for (int i=tid; i<64*32; i+=256){ int r=i>>5, c8=(i&31)*8;
      *(uint4*)(&Qs[r][c8]) = *(const uint4*)(Qbf + (size_t)(s*64+r)*256 + c8); }
  for (int i=tid; i<16*264; i+=256) hS[i/264][i%264] = f2b(0.f);
  const float gw_c = (s<8)? b2f(gwC[s]) : 0.f;
  float creg[4] = {0.f,0.f,0.f,0.f};
  __syncthreads();

  for (int t=0; t<96; ++t){
    // prefetch zc / SzM for this step (independent of h -> overlaps barA wait)
    f32x4 acc;
#pragma unroll
    for (int rr=0; rr<4; ++rr)
      acc[rr] = __half2float(zc[((size_t)(t*128)+r0+q*4+rr)*1024 + n0 + W*16 + cl]);
    f32x4 sa = {0.f,0.f,0.f,0.f};
    if (s<8){
#pragma unroll
      for (int rr=0; rr<4; ++rr)
        sa[rr] = __half2float(SzM[((size_t)(t*128)+r0+q*4+rr)*512 + s*64 + W*16 + cl]);
    }
    if (t>0){
      if (tid==0){ while (ld_flag(barp+0) < GRP*t) {} }
      __syncthreads();              // h(t-1) at LLC
      const bf16_t* hsrc = hSeq + (size_t)t*128*256;
      u32x4 a0 = ld_cg(hsrc + (size_t)(r0 + (tid>>5))*256 + (tid&31)*8);
      u32x4 a1 = ld_cg(hsrc + (size_t)(r0 + 8 + (tid>>5))*256 + (tid&31)*8);
      vm_wait0();
      *(u32x4*)(&hS[tid>>5][(tid&31)*8]) = a0;
      *(u32x4*)(&hS[8 + (tid>>5)][(tid&31)*8]) = a1;
      __syncthreads();
    }
    // cluster blocks: scores = SzM + h @ Q^T, softmax over 64 slots, publish t
    if (s<8){
#pragma unroll
      for (int ks=0; ks<8; ++ks){
        bf16x8 a = ld_frag(&hS[cl][ks*32 + q*8]);
        bf16x8 b = ld_frag(&Qs[W*16+cl][ks*32 + q*8]);
        sa = mfma_bf16(a, b, sa);
      }
      // per-row max over 64 cols = (16 lanes cl) x (4 waves)
#pragma unroll
      for (int rr=0; rr<4; ++rr){
        float m = sa[rr];
        m = fmaxf(m, __shfl_xor(m,1));
        m = fmaxf(m, __shfl_xor(m,2));
        m = fmaxf(m, __shfl_xor(m,4));
        m = fmaxf(m, __shfl_xor(m,8));
        if (cl==0) redmx[W][q*4+rr] = m;
      }
      __syncthreads();
      float e4[4];
#pragma unroll
      for (int rr=0; rr<4; ++rr){
        int row = q*4+rr;
        float mx = fmaxf(fmaxf(redmx[0][row],redmx[1][row]),
                         fmaxf(redmx[2][row],redmx[3][row]));
        float e = expf(sa[rr]-mx);
        e4[rr] = e;
        float ss = e;
        ss += __shfl_xor(ss,1); ss += __shfl_xor(ss,2);
        ss += __shfl_xor(ss,4); ss += __shfl_xor(ss,8);
        if (cl==0) redsm[W][row] = ss;
      }
      __syncthreads();
#pragma unroll
      for (int rr=0; rr<4; ++rr){
        int row = q*4+rr;
        float sm = redsm[0][row]+redsm[1][row]+redsm[2][row]+redsm[3][row];
        tO[row][W*16 + cl] = f2b(e4[rr]*gw_c/sm);
      }
      __syncthreads();
      if (tid < 128){               // coalesced coherent flush of t tile
        int r = tid>>3, c8 = (tid&7)*8;
        u32x4 v = *(u32x4*)(&tO[r][c8]);
        st_cg(tSeq + (size_t)t*128*512 + (size_t)(r0+r)*512 + s*64 + c8, v);
      }
      vm_wait0();
      __syncthreads();
      if (tid==0) atomicAdd(barp+16, 1);
    }
    // gate h-part overlapped with barB wait: nothing before barB needs it
#pragma unroll
    for (int ks=0; ks<8; ++ks){
      bf16x8 a = ld_frag(&hS[cl][ks*32 + q*8]);
      bf16x8 b = ld_frag(&Us[W*16+cl][ks*32 + q*8]);
      acc = mfma_bf16(a, b, acc);
    }
    if (tid==0){ while (ld_flag(barp+16) < 8*(t+1)) {} }
    __syncthreads();                // t at LLC
    {
      const bf16_t* tsrc = tSeq + (size_t)t*128*512;
      u32x4 b0 = ld_cg(tsrc + (size_t)(r0 + (tid>>6)     )*512 + (tid&63)*8);
      u32x4 b1 = ld_cg(tsrc + (size_t)(r0 + (tid>>6) +  4)*512 + (tid&63)*8);
      u32x4 b2 = ld_cg(tsrc + (size_t)(r0 + (tid>>6) +  8)*512 + (tid&63)*8);
      u32x4 b3 = ld_cg(tsrc + (size_t)(r0 + (tid>>6) + 12)*512 + (tid&63)*8);
      vm_wait0();
      *(u32x4*)(&tS[(tid>>6)     ][(tid&63)*8]) = b0;
      *(u32x4*)(&tS[(tid>>6) +  4][(tid&63)*8]) = b1;
      *(u32x4*)(&tS[(tid>>6) +  8][(tid&63)*8]) = b2;
      *(u32x4*)(&tS[(tid>>6) + 12][(tid&63)*8]) = b3;
      __syncthreads();
    }
    // gate gd-part: acc += t @ G^T
#pragma unroll
    for (int ks=0; ks<16; ++ks){
      bf16x8 a = ld_frag(&tS[cl][ks*32 + q*8]);
      bf16x8 b = ld_frag(&Gs[W*16+cl][ks*32 + q*8]);
      acc = mfma_bf16(a, b, acc);
    }
    // LSTM update: lanes quad = (i,f,o,c) of one j
    const int base = l & ~3;
#pragma unroll
    for (int rr=0; rr<4; ++rr){
      float p = acc[rr];
      float pi = __shfl(p, base+0);
      float pf = __shfl(p, base+1);
      float po = __shfl(p, base+2);
      float pc = __shfl(p, base+3);
      float iv = 1.f/(1.f+expf(-pi));
      float fv = 1.f/(1.f+expf(-pf));
      float ov = 1.f/(1.f+expf(-po));
      float cv = tanhf(pc);
      float cn = fv*creg[rr] + iv*cv;
      creg[rr] = cn;
      float hv = ov * tanhf(cn);
      if ((l&3)==0)
        hO[q*4+rr][W*4 + (cl>>2)] = f2b(hv);
    }
    __syncthreads();
    if (tid < 32){                  // coalesced coherent flush of h tile
      int r = tid>>1, c8 = (tid&1)*8;
      u32x4 v = *(u32x4*)(&hO[r][c8]);
      st_cg(hSeq + (size_t)(t+1)*128*256 + (size_t)(r0+r)*256 + s*16 + c8, v);
    }
    vm_wait0();
    __syncthreads();
    if (tid==0) atomicAdd(barp+0, 1);
  }
}

extern "C" void kernel_launch(void* const* d_in, const int* in_sizes, int n_in,
                              void* d_out, int out_size, void* d_ws, size_t ws_size,
                              hipStream_t stream)
{
  const void* x       = d_in[0];
  const void* Xmean   = d_in[1];
  const int*  clusters= (const int*)d_in[2];
  const void* Wi  = d_in[3];
  const void* bi  = d_in[4];
  const void* Wf  = d_in[5];
  const void* bfp = d_in[6];
  const void* Wo  = d_in[7];
  const void* bo  = d_in[8];
  const void* Wc  = d_in[9];
  const void* bcp = d_in[10];
  const void* Wfc = d_in[11];
  const void* bfc = d_in[12];
  const void* gzw = d_in[13];
  const void* gzb = d_in[14];
  const void* gzpw= d_in[15];
  const void* gzpb= d_in[16];
  const void* memory = d_in[17];
  const void* localw = d_in[18];
  const void* globalw= d_in[19];
  (void)in_sizes; (void)n_in; (void)out_size; (void)ws_size;

  char* ws = (char*)d_ws;
  size_t off = 0;
  auto take = [&](size_t bytes)->char*{
    char* p = ws + off; off = (off + bytes + 255) & ~(size_t)255; return p; };
  int*    flags  = (int*)   take(16);
  int*    bar    = (int*)   take(256*4);
  bf16_t* U      = (bf16_t*)take((size_t)1024*512*2);     // 1 MB
  bf16_t* Uz     = (bf16_t*)take((size_t)1024*512*2);     // 1 MB
  bf16_t* G      = (bf16_t*)take((size_t)1024*512*2);     // 1 MB
  bf16_t* WfcC   = (bf16_t*)take((size_t)65536*2);
  bf16_t* XmC    = (bf16_t*)take((size_t)24576*2);
  bf16_t* bfcC   = (bf16_t*)take(256*2);
  bf16_t* lwC    = (bf16_t*)take(768*2);
  bf16_t* gwC    = (bf16_t*)take(8*2);
  float*  gzC    = (float*) take(1024*4);
  float*  bias2  = (float*) take(1024*4);
  bf16_t* Mem2   = (bf16_t*)take((size_t)512*256*2);      // 256 KB
  bf16_t* Qbf    = (bf16_t*)take((size_t)512*256*2);      // 256 KB
  float*  qb     = (float*) take(512*4);
  __half* zc     = (__half*)take((size_t)12288*1024*2);   // 25.2 MB
  __half* SzM    = (__half*)take((size_t)12288*512*2);    // 12.6 MB
  // aliased regions (strictly sequential producers/consumers in-stream):
  //   bigA: Zcat (k_zzp->k_zc) then tSeq (k_main)        -- both 12.58 MB
  //   bigB: Zl   (k_zzp->k_szm) then hSeq (k_main->k_out)
  char* bigA = take((size_t)12288*512*2);
  char* bigB = take((size_t)97*128*256*2);
  bf16_t* Zcat = (bf16_t*)bigA;
  bf16_t* tSeq = (bf16_t*)bigA;
  bf16_t* Zl   = (bf16_t*)bigB;
  bf16_t* hSeq = (bf16_t*)bigB;

  k_detect<<<1,    64, 0,stream>>>((const uint32_t*)x, (const uint32_t*)clusters, flags);
  k_zero  <<<1,    256,0,stream>>>(bar);
  k_canon <<<256,  256,0,stream>>>(Wfc, Xmean, bfc, localw, globalw,
                                   gzw, gzb, gzpw, gzpb, flags,
                                   WfcC, XmC, bfcC, lwC, gwC, gzC);
  k_fold  <<<1024, 256,0,stream>>>(Wi,Wf,Wo,Wc, bi,bfp,bo,bcp, Wfc,bfc, flags,
                                   U, Uz, bias2);
  k_foldG <<<256,  256,0,stream>>>(Wi,Wf,Wo,Wc, memory, flags, G);
  k_foldQ <<<512,  256,0,stream>>>(clusters, memory, lwC, WfcC, bfcC, flags,
                                   Mem2, Qbf, qb);
  k_zzp   <<<12288,256,0,stream>>>(x, XmC, gzC, lwC, flags, Zcat, Zl);
  k_zc    <<<dim3(96,8),256,0,stream>>>(Zcat, Uz, bias2, zc);
  k_szm   <<<dim3(96,4),256,0,stream>>>(Zl, Mem2, qb, SzM);
  k_main  <<<128,  256,0,stream>>>(gwC, U, G, Qbf, zc, SzM, hSeq, tSeq, bar);
  k_out   <<<dim3(96,2),256,0,stream>>>(hSeq, WfcC, bfcC, flags, d_out);
}